// Round 2
// baseline (241.272 us; speedup 1.0000x reference)
//
#include <hip/hip_runtime.h>

// Haar forward: input (B=8, C=64, H=512, W=512) fp32 NCHW
// output (B, 4, C, 256, 256) flattened as (B, 4*C, h, w), subband-major.
// Per 2x2 block {a=x[2i,2j], b=x[2i,2j+1], c=x[2i+1,2j], d=x[2i+1,2j+1]}:
//   LL = .25*(a+b+c+d), k1 = .25*(a-b+c-d), k2 = .25*(a+b-c-d), k3 = .25*(a-b-c+d)
//
// Work item = one float4 of input per row-pair (4 input cols = 2 output pixels).
// Lane l loads at byte offset 16*l -> fully dense 1KiB/wave load instructions.
// j-chunks per row = 128 (pow2, multiple of 64) -> each wave has uniform
// (image m, rowpair i) and contiguous j range; loads AND stores dense.

constexpr int B  = 8;
constexpr int C  = 64;
constexpr int H  = 512;
constexpr int W  = 512;
constexpr int HO = H / 2;        // 256
constexpr int WO = W / 2;        // 256
constexpr int JC = W / 4;        // 128 float4 chunks per input row
constexpr int TOTAL = B * C * HO * JC;   // 16,777,216 work items

__global__ __launch_bounds__(256) void haar_fwd(const float* __restrict__ x,
                                                float* __restrict__ y) {
    const int stride = gridDim.x * blockDim.x;
    const size_t plane = (size_t)HO * WO;          // 65536
    for (int idx = blockIdx.x * blockDim.x + threadIdx.x; idx < TOTAL; idx += stride) {
        const int j = idx & (JC - 1);              // chunk within row  (0..127)
        const int i = (idx >> 7) & (HO - 1);       // row pair          (0..255)
        const int m = idx >> 15;                   // image = b*C + c   (0..511)

        const float* p0 = x + ((size_t)m * H + 2 * (size_t)i) * W + 4 * (size_t)j;
        const float4 r0 = *reinterpret_cast<const float4*>(p0);
        const float4 r1 = *reinterpret_cast<const float4*>(p0 + W);

        // pixel 0: a=r0.x b=r0.y c=r1.x d=r1.y ; pixel 1: a=r0.z b=r0.w c=r1.z d=r1.w
        const float s0 = r0.x + r0.y, d0 = r0.x - r0.y;   // row0 sums/diffs, pixel 0
        const float t0 = r0.z + r0.w, e0 = r0.z - r0.w;   // pixel 1
        const float s1 = r1.x + r1.y, d1 = r1.x - r1.y;   // row1
        const float t1 = r1.z + r1.w, e1 = r1.z - r1.w;

        float2 ll, k1, k2, k3;
        ll.x = 0.25f * (s0 + s1);  ll.y = 0.25f * (t0 + t1);
        k1.x = 0.25f * (d0 + d1);  k1.y = 0.25f * (e0 + e1);
        k2.x = 0.25f * (s0 - s1);  k2.y = 0.25f * (t0 - t1);
        k3.x = 0.25f * (d0 - d1);  k3.y = 0.25f * (e0 - e1);

        // output base: plane ((b*4 + 0)*C + c), row i, col 2*j
        const int bimg = m >> 6;                   // b
        const int cimg = m & (C - 1);              // c
        float* yb = y + ((size_t)bimg * 4 * C + cimg) * plane
                      + (size_t)i * WO + 2 * (size_t)j;

        *reinterpret_cast<float2*>(yb)                         = ll;
        *reinterpret_cast<float2*>(yb + (size_t)C * plane)     = k1;
        *reinterpret_cast<float2*>(yb + (size_t)2 * C * plane) = k2;
        *reinterpret_cast<float2*>(yb + (size_t)3 * C * plane) = k3;
    }
}

extern "C" void kernel_launch(void* const* d_in, const int* in_sizes, int n_in,
                              void* d_out, int out_size, void* d_ws, size_t ws_size,
                              hipStream_t stream) {
    const float* x = (const float*)d_in[0];
    float* y = (float*)d_out;

    const int threads = 256;
    const int blocks = 2048;    // 8192 waves = 256 CU x 32 waves/CU; 32 items/thread
    haar_fwd<<<blocks, threads, 0, stream>>>(x, y);
}

// Round 4
// 192.246 us; speedup vs baseline: 1.2550x; 1.2550x over previous
//
#include <hip/hip_runtime.h>

// Haar forward: input (B=8, C=64, H=512, W=512) fp32 NCHW
// output (B, 4, C, 256, 256) flattened as (B, 4*C, h, w), subband-major.
// Per 2x2 block {a=x[2i,2j], b=x[2i,2j+1], c=x[2i+1,2j], d=x[2i+1,2j+1]}:
//   LL = .25*(a+b+c+d), k1 = .25*(a-b+c-d), k2 = .25*(a+b-c-d), k3 = .25*(a-b-c+d)
//
// R1 structure (best so far: 211 us) + R4: non-temporal hints via native
// ext_vector_type (HIP float4 is a struct; the builtin rejects it).

constexpr int B  = 8;
constexpr int C  = 64;
constexpr int H  = 512;
constexpr int W  = 512;
constexpr int HO = H / 2;   // 256
constexpr int WO = W / 2;   // 256
constexpr int W4 = WO / 4;  // 64 float4-chunks per output row

typedef float f32x4 __attribute__((ext_vector_type(4)));

__global__ __launch_bounds__(256) void haar_fwd(const float* __restrict__ x,
                                                float* __restrict__ y) {
    const int total = B * C * HO * W4;
    int idx = blockIdx.x * blockDim.x + threadIdx.x;
    if (idx >= total) return;

    const int j4 = idx & (W4 - 1);          // 0..63
    const int i  = (idx >> 6) & (HO - 1);   // 0..255
    const int m  = idx >> 14;               // image = b*C + c (0..511)

    const float* r0 = x + ((size_t)m * H + 2 * (size_t)i) * W + 8 * (size_t)j4;
    const float* r1 = r0 + W;
    const f32x4 r0a = __builtin_nontemporal_load(reinterpret_cast<const f32x4*>(r0));
    const f32x4 r0b = __builtin_nontemporal_load(reinterpret_cast<const f32x4*>(r0 + 4));
    const f32x4 r1a = __builtin_nontemporal_load(reinterpret_cast<const f32x4*>(r1));
    const f32x4 r1b = __builtin_nontemporal_load(reinterpret_cast<const f32x4*>(r1 + 4));

    // Pixel p: a=row0[2p], b=row0[2p+1], c=row1[2p], d=row1[2p+1]
    const float a0 = r0a.x, b0 = r0a.y, a1 = r0a.z, b1 = r0a.w;
    const float a2 = r0b.x, b2 = r0b.y, a3 = r0b.z, b3 = r0b.w;
    const float c0 = r1a.x, d0 = r1a.y, c1 = r1a.z, d1 = r1a.w;
    const float c2 = r1b.x, d2 = r1b.y, c3 = r1b.z, d3 = r1b.w;

    f32x4 ll, k1, k2, k3;
    ll.x = 0.25f * (a0 + b0 + c0 + d0);
    ll.y = 0.25f * (a1 + b1 + c1 + d1);
    ll.z = 0.25f * (a2 + b2 + c2 + d2);
    ll.w = 0.25f * (a3 + b3 + c3 + d3);

    k1.x = 0.25f * (a0 - b0 + c0 - d0);
    k1.y = 0.25f * (a1 - b1 + c1 - d1);
    k1.z = 0.25f * (a2 - b2 + c2 - d2);
    k1.w = 0.25f * (a3 - b3 + c3 - d3);

    k2.x = 0.25f * (a0 + b0 - c0 - d0);
    k2.y = 0.25f * (a1 + b1 - c1 - d1);
    k2.z = 0.25f * (a2 + b2 - c2 - d2);
    k2.w = 0.25f * (a3 + b3 - c3 - d3);

    k3.x = 0.25f * (a0 - b0 - c0 + d0);
    k3.y = 0.25f * (a1 - b1 - c1 + d1);
    k3.z = 0.25f * (a2 - b2 - c2 + d2);
    k3.w = 0.25f * (a3 - b3 - c3 + d3);

    const size_t plane  = (size_t)HO * WO;
    const size_t rowoff = (size_t)i * WO + 4 * (size_t)j4;
    float* yb = y + ((size_t)(m >> 6) * 4 * C + (m & (C - 1))) * plane + rowoff;

    __builtin_nontemporal_store(ll, reinterpret_cast<f32x4*>(yb));
    __builtin_nontemporal_store(k1, reinterpret_cast<f32x4*>(yb + (size_t)C * plane));
    __builtin_nontemporal_store(k2, reinterpret_cast<f32x4*>(yb + (size_t)2 * C * plane));
    __builtin_nontemporal_store(k3, reinterpret_cast<f32x4*>(yb + (size_t)3 * C * plane));
}

extern "C" void kernel_launch(void* const* d_in, const int* in_sizes, int n_in,
                              void* d_out, int out_size, void* d_ws, size_t ws_size,
                              hipStream_t stream) {
    const float* x = (const float*)d_in[0];
    float* y = (float*)d_out;

    const int total = B * C * HO * W4;   // 8,388,608 threads
    const int threads = 256;
    const int blocks = (total + threads - 1) / threads;   // 32768
    haar_fwd<<<blocks, threads, 0, stream>>>(x, y);
}